// Round 1
// baseline (1584.714 us; speedup 1.0000x reference)
//
#include <hip/hip_runtime.h>

#define NN 10000
#define EE 160000
#define DD 128          // input dim == embedding channels
#define KT 4

constexpr int JSPLIT = 16;
constexpr int ITILES = (NN + 63) / 64;            // 157
constexpr int JCHUNK = (NN + JSPLIT - 1) / JSPLIT; // 625
constexpr double FPSCALE = 1099511627776.0;        // 2^40
constexpr float NEG_INF = -3.402823466e38f;

// -------------------- h0 = x @ W --------------------
__global__ void k_gemm(const float* __restrict__ x, const float* __restrict__ W,
                       float* __restrict__ hpre) {
    int row = blockIdx.x;
    int c = threadIdx.x;   // 128
    __shared__ float xs[DD];
    xs[c] = x[row * DD + c];
    __syncthreads();
    float acc = 0.f;
#pragma unroll 8
    for (int k = 0; k < DD; ++k) acc += xs[k] * W[k * DD + c];
    hpre[row * DD + c] = acc;
}

// -------------------- degree (row side only, per reference) --------------------
__global__ void k_deg(const int* __restrict__ erow, float* __restrict__ deg) {
    int e = blockIdx.x * blockDim.x + threadIdx.x;
    if (e < EE) atomicAdd(&deg[erow[e]], 1.0f);
}

__global__ void k_dinv(const float* __restrict__ deg, float* __restrict__ dinv) {
    int i = blockIdx.x * blockDim.x + threadIdx.x;
    if (i < NN) {
        float d = deg[i] + 1.0f;  // + self loop
        dinv[i] = 1.0f / sqrtf(fmaxf(d, 1e-12f));
    }
}

// -------------------- self-loop contribution (plain store into fixed-point acc) ----
__global__ void k_self(const float* __restrict__ hpre, const float* __restrict__ dinv,
                       long long* __restrict__ acc) {
    int t = blockIdx.x * blockDim.x + threadIdx.x;
    if (t < NN * DD) {
        int i = t >> 7;
        float v = hpre[t] * dinv[i] * dinv[i];
        acc[t] = (long long)llrint((double)v * FPSCALE);
    }
}

// -------------------- edge aggregation: deterministic fixed-point atomics ----------
__global__ void k_agg(const int* __restrict__ ei, const float* __restrict__ hpre,
                      const float* __restrict__ dinv, unsigned long long* __restrict__ acc) {
    int t = blockIdx.x * blockDim.x + threadIdx.x;   // EE*32 threads, 4 ch each
    if (t >= EE * 32) return;
    int e = t >> 5;
    int c4 = (t & 31) << 2;
    int r = ei[e];        // destination (segment row)
    int c = ei[EE + e];   // source
    float w = dinv[r] * dinv[c];
    const float4 hv = *reinterpret_cast<const float4*>(&hpre[c * DD + c4]);
    unsigned long long* dst = &acc[r * DD + c4];
    atomicAdd(dst + 0, (unsigned long long)(long long)llrint((double)(hv.x * w) * FPSCALE));
    atomicAdd(dst + 1, (unsigned long long)(long long)llrint((double)(hv.y * w) * FPSCALE));
    atomicAdd(dst + 2, (unsigned long long)(long long)llrint((double)(hv.z * w) * FPSCALE));
    atomicAdd(dst + 3, (unsigned long long)(long long)llrint((double)(hv.w * w) * FPSCALE));
}

// -------------------- finalize h = acc/2^40 + b --------------------
__global__ void k_hfin(const long long* __restrict__ acc, const float* __restrict__ b,
                       float* __restrict__ hout) {
    int t = blockIdx.x * blockDim.x + threadIdx.x;
    if (t < NN * DD) {
        float v = (float)((double)acc[t] * (1.0 / FPSCALE));
        hout[t] = v + b[t & 127];
    }
}

// -------------------- row squared norms --------------------
__global__ void k_sq(const float* __restrict__ h, float* __restrict__ sq) {
    int i = blockIdx.x;
    int l = threadIdx.x;  // 64
    float a = h[i * DD + l];
    float b2 = h[i * DD + 64 + l];
    float s = a * a + b2 * b2;
#pragma unroll
    for (int off = 32; off; off >>= 1) s += __shfl_xor(s, off, 64);
    if (l == 0) sq[i] = s;
}

// -------------------- top-k over lq = -T*max(sq_i+sq_j-2<hi,hj>,0) + gumbel(q) ------
#define BETTER(v1, j1, v2, j2) ((v1) > (v2) || ((v1) == (v2) && (j1) < (j2)))

__global__ __launch_bounds__(256, 2) void k_topk(
    const float* __restrict__ h, const float* __restrict__ sq,
    const float* __restrict__ q, const float* __restrict__ tptr,
    float* __restrict__ pvals, int* __restrict__ pidx) {
    __shared__ float Ash[64 * 128];
    __shared__ float Bsh[64 * 128];

    const int blk = blockIdx.x;
    const int itile = blk / JSPLIT;
    const int split = blk - itile * JSPLIT;
    const int ibase = itile * 64;
    const int jstart = split * JCHUNK;
    const int jend = min(NN, jstart + JCHUNK);
    const float T = *tptr;
    const int tid = threadIdx.x;
    const int tj = tid & 15;
    const int ti = tid >> 4;

    // stage A tile (64 rows x 128), XOR-swizzled float4 columns
#pragma unroll
    for (int p = 0; p < 8; ++p) {
        int idx = p * 256 + tid;
        int row = idx >> 5, kb4 = idx & 31;
        int g = ibase + row;
        float4 v = make_float4(0.f, 0.f, 0.f, 0.f);
        if (g < NN) v = *reinterpret_cast<const float4*>(&h[g * DD + kb4 * 4]);
        int sw = kb4 ^ ((row & 7) ^ (row >> 3));
        *reinterpret_cast<float4*>(&Ash[row * 128 + sw * 4]) = v;
    }

    // per-thread constants
    int baseA[4], xA[4], baseB[4], xB[4];
    float sqi[4];
#pragma unroll
    for (int r = 0; r < 4; ++r) {
        int rowA = ti + 16 * r;
        baseA[r] = rowA * 128;
        xA[r] = (rowA & 7) ^ (rowA >> 3);
        int rowB = tj + 16 * r;
        baseB[r] = rowB * 128;
        xB[r] = (rowB & 7) ^ (rowB >> 3);
        int i = ibase + rowA;
        sqi[r] = (i < NN) ? sq[i] : 0.f;
    }

    float tv[4][4];
    int tjx[4][4];
#pragma unroll
    for (int a = 0; a < 4; ++a)
#pragma unroll
        for (int b = 0; b < 4; ++b) { tv[a][b] = NEG_INF; tjx[a][b] = 0x7fffffff; }

    const int ntiles = (jend - jstart + 63) >> 6;
    for (int jt = 0; jt < ntiles; ++jt) {
        int jbase = jstart + jt * 64;
        __syncthreads();  // previous-iter Bsh reads done
#pragma unroll
        for (int p = 0; p < 8; ++p) {
            int idx = p * 256 + tid;
            int row = idx >> 5, kb4 = idx & 31;
            int g = jbase + row;
            float4 v = make_float4(0.f, 0.f, 0.f, 0.f);
            if (g < NN) v = *reinterpret_cast<const float4*>(&h[g * DD + kb4 * 4]);
            int sw = kb4 ^ ((row & 7) ^ (row >> 3));
            *reinterpret_cast<float4*>(&Bsh[row * 128 + sw * 4]) = v;
        }
        __syncthreads();

        float acc[4][4];
#pragma unroll
        for (int a = 0; a < 4; ++a)
#pragma unroll
            for (int b = 0; b < 4; ++b) acc[a][b] = 0.f;

        for (int kk = 0; kk < 32; ++kk) {
            float4 av[4], bv[4];
#pragma unroll
            for (int r = 0; r < 4; ++r) {
                av[r] = *reinterpret_cast<const float4*>(&Ash[baseA[r] + ((kk ^ xA[r]) << 2)]);
                bv[r] = *reinterpret_cast<const float4*>(&Bsh[baseB[r] + ((kk ^ xB[r]) << 2)]);
            }
#pragma unroll
            for (int a = 0; a < 4; ++a)
#pragma unroll
                for (int b = 0; b < 4; ++b) {
                    acc[a][b] += av[a].x * bv[b].x;
                    acc[a][b] += av[a].y * bv[b].y;
                    acc[a][b] += av[a].z * bv[b].z;
                    acc[a][b] += av[a].w * bv[b].w;
                }
        }

        // epilogue: lq + top-4 update
#pragma unroll
        for (int b = 0; b < 4; ++b) {
            int j = jbase + tj + 16 * b;
            bool jvalid = (j < jend);
            float sqj = jvalid ? sq[j] : 0.f;
#pragma unroll
            for (int a = 0; a < 4; ++a) {
                int i = ibase + ti + 16 * a;
                if (jvalid && i < NN) {
                    float d2 = fmaxf(sqi[a] + sqj - 2.f * acc[a][b], 0.f);
                    float qv = q[(size_t)i * NN + j];
                    float g = -logf(-logf(qv + 1e-8f));
                    float v = fmaf(-T, d2, g);
                    if (BETTER(v, j, tv[a][3], tjx[a][3])) {
                        tv[a][3] = v; tjx[a][3] = j;
#pragma unroll
                        for (int rr = 3; rr > 0; --rr) {
                            if (BETTER(tv[a][rr], tjx[a][rr], tv[a][rr - 1], tjx[a][rr - 1])) {
                                float t0 = tv[a][rr]; tv[a][rr] = tv[a][rr - 1]; tv[a][rr - 1] = t0;
                                int t1 = tjx[a][rr]; tjx[a][rr] = tjx[a][rr - 1]; tjx[a][rr - 1] = t1;
                            }
                        }
                    }
                }
            }
        }
    }

    // in-block merge across the 16 tj threads per row
    __syncthreads();
    int* Bi = reinterpret_cast<int*>(Bsh);
#pragma unroll
    for (int a = 0; a < 4; ++a) {
        int row = ti + 16 * a;
#pragma unroll
        for (int r = 0; r < 4; ++r) {
            Ash[row * 64 + tj * 4 + r] = tv[a][r];
            Bi[row * 64 + tj * 4 + r] = tjx[a][r];
        }
    }
    __syncthreads();
    if (tid < 64) {
        int row = tid;
        int i = ibase + row;
        float mv[4] = {NEG_INF, NEG_INF, NEG_INF, NEG_INF};
        int mj[4] = {0x7fffffff, 0x7fffffff, 0x7fffffff, 0x7fffffff};
        for (int c = 0; c < 64; ++c) {
            float v = Ash[row * 64 + c];
            int j = Bi[row * 64 + c];
            if (BETTER(v, j, mv[3], mj[3])) {
                mv[3] = v; mj[3] = j;
#pragma unroll
                for (int rr = 3; rr > 0; --rr) {
                    if (BETTER(mv[rr], mj[rr], mv[rr - 1], mj[rr - 1])) {
                        float t0 = mv[rr]; mv[rr] = mv[rr - 1]; mv[rr - 1] = t0;
                        int t1 = mj[rr]; mj[rr] = mj[rr - 1]; mj[rr - 1] = t1;
                    }
                }
            }
        }
        if (i < NN) {
#pragma unroll
            for (int r = 0; r < 4; ++r) {
                pvals[(split * NN + i) * 4 + r] = mv[r];
                pidx[(split * NN + i) * 4 + r] = mj[r];
            }
        }
    }
}

// -------------------- final cross-split merge + output assembly --------------------
__global__ void k_merge(const float* __restrict__ pvals, const int* __restrict__ pidx,
                        float* __restrict__ out) {
    int i = blockIdx.x * blockDim.x + threadIdx.x;
    if (i >= NN) return;
    float mv[4] = {NEG_INF, NEG_INF, NEG_INF, NEG_INF};
    int mj[4] = {0x7fffffff, 0x7fffffff, 0x7fffffff, 0x7fffffff};
    for (int s = 0; s < JSPLIT; ++s) {
#pragma unroll
        for (int r = 0; r < 4; ++r) {
            float v = pvals[(s * NN + i) * 4 + r];
            int j = pidx[(s * NN + i) * 4 + r];
            if (BETTER(v, j, mv[3], mj[3])) {
                mv[3] = v; mj[3] = j;
#pragma unroll
                for (int rr = 3; rr > 0; --rr) {
                    if (BETTER(mv[rr], mj[rr], mv[rr - 1], mj[rr - 1])) {
                        float t0 = mv[rr]; mv[rr] = mv[rr - 1]; mv[rr - 1] = t0;
                        int t1 = mj[rr]; mj[rr] = mj[rr - 1]; mj[rr - 1] = t1;
                    }
                }
            }
        }
    }
    // d_out layout: h [0, 1_280_000) | edges [1_280_000, 1_380_000) | logprobs [1_380_000, 1_420_000)
    float* eidx = out + NN * DD;        // edge row 0: [idx.flatten() (40000), arange (10000)]
    float* erow = eidx + (NN * KT + NN);// edge row 1: [repeat(arange,4) (40000), arange (10000)]
    float* lp = erow + (NN * KT + NN);
#pragma unroll
    for (int r = 0; r < 4; ++r) {
        eidx[i * 4 + r] = (float)mj[r];
        erow[i * 4 + r] = (float)i;
        lp[i * 4 + r] = mv[r];
    }
    eidx[NN * KT + i] = (float)i;
    erow[NN * KT + i] = (float)i;
}

extern "C" void kernel_launch(void* const* d_in, const int* in_sizes, int n_in,
                              void* d_out, int out_size, void* d_ws, size_t ws_size,
                              hipStream_t stream) {
    const float* x = (const float*)d_in[0];
    const int* ei = (const int*)d_in[1];   // [2, E] int
    const float* q = (const float*)d_in[2];
    const float* W = (const float*)d_in[3];
    const float* b = (const float*)d_in[4];
    const float* temp = (const float*)d_in[5];
    float* out = (float*)d_out;

    char* ws = (char*)d_ws;
    float* hpre = (float*)(ws + 0);                        // 5,120,000 B
    long long* acc = (long long*)(ws + 5120000);           // 10,240,000 B
    float* deg = (float*)(ws + 15360000);                  // 40,000 B
    float* dinv = (float*)(ws + 15400000);                 // 40,000 B
    float* sq = (float*)(ws + 15440000);                   // 40,000 B
    float* pvals = (float*)(ws + 15480000);                // 2,560,000 B
    int* pidx = (int*)(ws + 18040000);                     // 2,560,000 B

    // zero acc + deg (poisoned 0xAA; not re-poisoned between replays)
    hipMemsetAsync(ws + 5120000, 0, 10240000 + 40000, stream);

    k_gemm<<<NN, 128, 0, stream>>>(x, W, hpre);
    k_deg<<<(EE + 255) / 256, 256, 0, stream>>>(ei, deg);
    k_dinv<<<(NN + 255) / 256, 256, 0, stream>>>(deg, dinv);
    k_self<<<(NN * DD + 255) / 256, 256, 0, stream>>>(hpre, dinv, acc);
    k_agg<<<(EE * 32 + 255) / 256, 256, 0, stream>>>(ei, hpre, dinv, (unsigned long long*)acc);
    k_hfin<<<(NN * DD + 255) / 256, 256, 0, stream>>>(acc, b, out);
    k_sq<<<NN, 64, 0, stream>>>(out, sq);
    k_topk<<<ITILES * JSPLIT, 256, 0, stream>>>(out, sq, q, temp, pvals, pidx);
    k_merge<<<(NN + 255) / 256, 256, 0, stream>>>(pvals, pidx, out);
}

// Round 2
// 1340.009 us; speedup vs baseline: 1.1826x; 1.1826x over previous
//
#include <hip/hip_runtime.h>

#define NN 10000
#define NPAD 10048
#define EE 160000
#define DD 128
#define KT 4

constexpr int JSPLIT = 16;
constexpr int ITILES = 157;               // ceil(10000/64)
constexpr int JCHUNK = 625;               // 10000/16
constexpr double FPSCALE = 1099511627776.0; // 2^40
constexpr float NEG_INF = -3.402823466e38f;

typedef __attribute__((ext_vector_type(8))) short short8;
typedef __attribute__((ext_vector_type(8))) unsigned short ushort8;
typedef __attribute__((ext_vector_type(4))) float f32x4;

// -------------------- bf16 split helpers --------------------
__device__ inline unsigned short bf_rn(float x) {
    unsigned u = __float_as_uint(x);
    unsigned r = (u + 0x7fffu + ((u >> 16) & 1u)) >> 16;
    return (unsigned short)r;
}
__device__ inline float bf_f(unsigned short h) {
    return __uint_as_float(((unsigned)h) << 16);
}

// -------------------- fast accurate ln for x in (1e-8, 20) --------------------
// atanh-series; direct path (no exponent split) near 1 keeps relative accuracy
// through the catastrophic-cancellation zone. Max rel err ~1.5e-7 (t^12/13 tail).
__device__ inline float fast_ln(float x) {
    int bits = __float_as_int(x);
    int e = ((bits >> 23) & 0xff) - 127;
    float m = __int_as_float((bits & 0x007fffff) | 0x3f800000); // [1,2)
    bool direct = (x > 0.6875f) && (x < 1.375f);
    float xm = direct ? x : m;
    float ef = direct ? 0.f : (float)e;
    float t = (xm - 1.f) * __builtin_amdgcn_rcpf(xm + 1.f);
    float t2 = t * t;
    float p = 0.09090909f;               // 1/11
    p = fmaf(p, t2, 0.11111111f);        // 1/9
    p = fmaf(p, t2, 0.14285714f);        // 1/7
    p = fmaf(p, t2, 0.2f);               // 1/5
    p = fmaf(p, t2, 0.33333333f);        // 1/3
    p = fmaf(p, t2, 1.f);
    p = 2.f * t * p;
    return fmaf(ef, 0.69314718055994531f, p);
}

// -------------------- h0 = x @ W --------------------
__global__ void k_gemm(const float* __restrict__ x, const float* __restrict__ W,
                       float* __restrict__ hpre) {
    int row = blockIdx.x;
    int c = threadIdx.x;   // 128
    __shared__ float xs[DD];
    xs[c] = x[row * DD + c];
    __syncthreads();
    float acc = 0.f;
#pragma unroll 8
    for (int k = 0; k < DD; ++k) acc += xs[k] * W[k * DD + c];
    hpre[row * DD + c] = acc;
}

// -------------------- degree --------------------
__global__ void k_deg(const int* __restrict__ erow, float* __restrict__ deg) {
    int e = blockIdx.x * blockDim.x + threadIdx.x;
    if (e < EE) atomicAdd(&deg[erow[e]], 1.0f);
}

__global__ void k_dinv(const float* __restrict__ deg, float* __restrict__ dinv) {
    int i = blockIdx.x * blockDim.x + threadIdx.x;
    if (i < NN) {
        float d = deg[i] + 1.0f;  // + self loop
        dinv[i] = 1.0f / sqrtf(fmaxf(d, 1e-12f));
    }
}

// -------------------- self-loop contribution --------------------
__global__ void k_self(const float* __restrict__ hpre, const float* __restrict__ dinv,
                       long long* __restrict__ acc) {
    int t = blockIdx.x * blockDim.x + threadIdx.x;
    if (t < NN * DD) {
        int i = t >> 7;
        float v = hpre[t] * dinv[i] * dinv[i];
        acc[t] = (long long)llrint((double)v * FPSCALE);
    }
}

// -------------------- edge aggregation: deterministic fixed-point atomics ----------
__global__ void k_agg(const int* __restrict__ ei, const float* __restrict__ hpre,
                      const float* __restrict__ dinv, unsigned long long* __restrict__ acc) {
    int t = blockIdx.x * blockDim.x + threadIdx.x;
    if (t >= EE * 32) return;
    int e = t >> 5;
    int c4 = (t & 31) << 2;
    int r = ei[e];
    int c = ei[EE + e];
    float w = dinv[r] * dinv[c];
    const float4 hv = *reinterpret_cast<const float4*>(&hpre[c * DD + c4]);
    unsigned long long* dst = &acc[r * DD + c4];
    atomicAdd(dst + 0, (unsigned long long)(long long)llrint((double)(hv.x * w) * FPSCALE));
    atomicAdd(dst + 1, (unsigned long long)(long long)llrint((double)(hv.y * w) * FPSCALE));
    atomicAdd(dst + 2, (unsigned long long)(long long)llrint((double)(hv.z * w) * FPSCALE));
    atomicAdd(dst + 3, (unsigned long long)(long long)llrint((double)(hv.w * w) * FPSCALE));
}

// -------------------- finalize h = acc/2^40 + b --------------------
__global__ void k_hfin(const long long* __restrict__ acc, const float* __restrict__ b,
                       float* __restrict__ hout) {
    int t = blockIdx.x * blockDim.x + threadIdx.x;
    if (t < NN * DD) {
        float v = (float)((double)acc[t] * (1.0 / FPSCALE));
        hout[t] = v + b[t & 127];
    }
}

// -------------------- bf16 hi/lo split + row norms (padded to 10048 rows) ----------
__global__ void k_prep(const float* __restrict__ h, unsigned short* __restrict__ hhi,
                       unsigned short* __restrict__ hlo, float* __restrict__ sqout) {
    int row = blockIdx.x;      // 10048
    int c = threadIdx.x;       // 64
    float v0 = 0.f, v1 = 0.f;
    if (row < NN) { v0 = h[row * DD + c]; v1 = h[row * DD + 64 + c]; }
    unsigned short h0 = bf_rn(v0), h1 = bf_rn(v1);
    float r0 = v0 - bf_f(h0), r1 = v1 - bf_f(h1);
    unsigned short l0 = bf_rn(r0), l1 = bf_rn(r1);
    hhi[row * DD + c] = h0; hhi[row * DD + 64 + c] = h1;
    hlo[row * DD + c] = l0; hlo[row * DD + 64 + c] = l1;
    float s = v0 * v0 + v1 * v1;
#pragma unroll
    for (int off = 32; off; off >>= 1) s += __shfl_xor(s, off, 64);
    if (c == 0) sqout[row] = s;
}

#define BETTER(v1, j1, v2, j2) ((v1) > (v2) || ((v1) == (v2) && (j1) < (j2)))

// -------------------- MFMA bf16x3 pairwise-dist + gumbel + top-4 --------------------
// grid = 157 itiles x 16 jsplits; 4 waves, each owns a 16-row i-strip.
// B tile (64 x 128 bf16 hi+lo) staged in LDS with 16B-chunk XOR swizzle.
__global__ __launch_bounds__(256, 4) void k_topk(
    const unsigned short* __restrict__ hhi, const unsigned short* __restrict__ hlo,
    const float* __restrict__ sq, const float* __restrict__ q,
    const float* __restrict__ tptr, float* __restrict__ pvals, int* __restrict__ pidx) {
    __shared__ __align__(16) unsigned short Bhi[64 * DD];  // 16 KB
    __shared__ __align__(16) unsigned short Blo[64 * DD];  // 16 KB

    const int blk = blockIdx.x;
    const int itile = blk >> 4;
    const int split = blk & 15;
    const int ibase = itile * 64;
    const int jstart = split * JCHUNK;
    const float T = *tptr;

    const int tid = threadIdx.x;
    const int w = tid >> 6;
    const int lane = tid & 63;
    const int n = lane & 15;     // A-load row / B col / C col
    const int kl = lane >> 4;    // k-slice lane group; C row group

    // ---- A fragments (wave strip rows ibase+16w .. +15), held in regs ----
    short8 ahi[4], alo[4];
    {
        int ra = ibase + 16 * w + n;
        if (ra > NPAD - 1) ra = NPAD - 1;
        const unsigned short* pa = hhi + ra * DD + kl * 8;
        const unsigned short* pl = hlo + ra * DD + kl * 8;
#pragma unroll
        for (int ks = 0; ks < 4; ++ks) {
            ahi[ks] = *reinterpret_cast<const short8*>(pa + ks * 32);
            alo[ks] = *reinterpret_cast<const short8*>(pl + ks * 32);
        }
    }

    // ---- per-lane epilogue constants: rows i = ibase + 16w + kl*4 + r ----
    float sqi[4];
    const char* qrow[4];
#pragma unroll
    for (int r = 0; r < 4; ++r) {
        int i = ibase + 16 * w + kl * 4 + r;
        int ic = min(i, NN - 1);
        sqi[r] = sq[ic];
        qrow[r] = (const char*)q + (size_t)ic * (size_t)(NN * 4);
    }

    float tv[4][4];
    int tj[4][4];
#pragma unroll
    for (int r = 0; r < 4; ++r)
#pragma unroll
        for (int s = 0; s < 4; ++s) { tv[r][s] = NEG_INF; tj[r][s] = 0x7fffffff; }

    for (int jt = 0; jt < 10; ++jt) {
        const int jbase = jstart + jt * 64;
        __syncthreads();  // previous-tile LDS reads done
        // ---- stage B tile: 1024 16B chunks each for hi/lo; chunk cl of row -> phys cl^(row&7)
#pragma unroll
        for (int p = 0; p < 4; ++p) {
            int c = p * 256 + tid;
            int row = c >> 4, cl = c & 15;
            int cp = cl ^ (row & 7);
            int gsrc = (jbase + row) * DD + cl * 8;
            ushort8 vh = *reinterpret_cast<const ushort8*>(hhi + gsrc);
            ushort8 vl = *reinterpret_cast<const ushort8*>(hlo + gsrc);
            *reinterpret_cast<ushort8*>(&Bhi[row * DD + cp * 8]) = vh;
            *reinterpret_cast<ushort8*>(&Blo[row * DD + cp * 8]) = vl;
        }
        __syncthreads();

#pragma unroll
        for (int jf = 0; jf < 4; ++jf) {
            const int row = 16 * jf + n;
            const int xr = n & 7;
            f32x4 acc = {0.f, 0.f, 0.f, 0.f};
            short8 bh[4], bl[4];
#pragma unroll
            for (int ks = 0; ks < 4; ++ks) {
                int cp = (ks * 4 + kl) ^ xr;
                bh[ks] = *reinterpret_cast<const short8*>(&Bhi[row * DD + cp * 8]);
                bl[ks] = *reinterpret_cast<const short8*>(&Blo[row * DD + cp * 8]);
            }
#pragma unroll
            for (int ks = 0; ks < 4; ++ks)
                acc = __builtin_amdgcn_mfma_f32_16x16x32_bf16(ahi[ks], bh[ks], acc, 0, 0, 0);
#pragma unroll
            for (int ks = 0; ks < 4; ++ks)
                acc = __builtin_amdgcn_mfma_f32_16x16x32_bf16(ahi[ks], bl[ks], acc, 0, 0, 0);
#pragma unroll
            for (int ks = 0; ks < 4; ++ks)
                acc = __builtin_amdgcn_mfma_f32_16x16x32_bf16(alo[ks], bh[ks], acc, 0, 0, 0);

            // ---- epilogue: lq + running top-4 per row ----
            const int j = jbase + 16 * jf + n;
            const bool jv = (j - jstart) < JCHUNK;
            const int jc = min(j, NN - 1);
            const float sqj = sq[jc];
#pragma unroll
            for (int r = 0; r < 4; ++r) {
                float d2 = fmaxf(fmaf(-2.f, acc[r], sqi[r] + sqj), 0.f);
                float qv = *reinterpret_cast<const float*>(qrow[r] + (size_t)jc * 4);
                float u = -fast_ln(qv + 1e-8f);
                float g = -fast_ln(u);
                float v = jv ? fmaf(-T, d2, g) : NEG_INF;
                if (BETTER(v, j, tv[r][3], tj[r][3])) {
                    tv[r][3] = v; tj[r][3] = j;
#pragma unroll
                    for (int rr = 3; rr > 0; --rr) {
                        if (BETTER(tv[r][rr], tj[r][rr], tv[r][rr - 1], tj[r][rr - 1])) {
                            float t0 = tv[r][rr]; tv[r][rr] = tv[r][rr - 1]; tv[r][rr - 1] = t0;
                            int t1 = tj[r][rr]; tj[r][rr] = tj[r][rr - 1]; tj[r][rr - 1] = t1;
                        }
                    }
                }
            }
        }
    }

    // ---- in-block merge: 16 lanes (n) per row -> top-4 per row ----
    __syncthreads();
    float* mv = reinterpret_cast<float*>(Bhi);  // 64 rows x 64 entries
    int* mj = reinterpret_cast<int*>(Blo);
#pragma unroll
    for (int r = 0; r < 4; ++r) {
        int rl = 16 * w + kl * 4 + r;
#pragma unroll
        for (int s = 0; s < 4; ++s) {
            mv[rl * 64 + n * 4 + s] = tv[r][s];
            mj[rl * 64 + n * 4 + s] = tj[r][s];
        }
    }
    __syncthreads();
    if (tid < 64) {
        int i = ibase + tid;
        float bv[4] = {NEG_INF, NEG_INF, NEG_INF, NEG_INF};
        int bj[4] = {0x7fffffff, 0x7fffffff, 0x7fffffff, 0x7fffffff};
        for (int c = 0; c < 64; ++c) {
            int cc = (c + tid) & 63;  // rotate to avoid bank conflicts
            float v = mv[tid * 64 + cc];
            int j = mj[tid * 64 + cc];
            if (BETTER(v, j, bv[3], bj[3])) {
                bv[3] = v; bj[3] = j;
#pragma unroll
                for (int rr = 3; rr > 0; --rr) {
                    if (BETTER(bv[rr], bj[rr], bv[rr - 1], bj[rr - 1])) {
                        float t0 = bv[rr]; bv[rr] = bv[rr - 1]; bv[rr - 1] = t0;
                        int t1 = bj[rr]; bj[rr] = bj[rr - 1]; bj[rr - 1] = t1;
                    }
                }
            }
        }
        if (i < NN) {
#pragma unroll
            for (int s = 0; s < 4; ++s) {
                pvals[(split * NN + i) * 4 + s] = bv[s];
                pidx[(split * NN + i) * 4 + s] = bj[s];
            }
        }
    }
}

// -------------------- final cross-split merge + output assembly --------------------
__global__ void k_merge(const float* __restrict__ pvals, const int* __restrict__ pidx,
                        float* __restrict__ out) {
    int i = blockIdx.x * blockDim.x + threadIdx.x;
    if (i >= NN) return;
    float mv[4] = {NEG_INF, NEG_INF, NEG_INF, NEG_INF};
    int mj[4] = {0x7fffffff, 0x7fffffff, 0x7fffffff, 0x7fffffff};
    for (int s = 0; s < JSPLIT; ++s) {
#pragma unroll
        for (int r = 0; r < 4; ++r) {
            float v = pvals[(s * NN + i) * 4 + r];
            int j = pidx[(s * NN + i) * 4 + r];
            if (BETTER(v, j, mv[3], mj[3])) {
                mv[3] = v; mj[3] = j;
#pragma unroll
                for (int rr = 3; rr > 0; --rr) {
                    if (BETTER(mv[rr], mj[rr], mv[rr - 1], mj[rr - 1])) {
                        float t0 = mv[rr]; mv[rr] = mv[rr - 1]; mv[rr - 1] = t0;
                        int t1 = mj[rr]; mj[rr] = mj[rr - 1]; mj[rr - 1] = t1;
                    }
                }
            }
        }
    }
    float* eidx = out + NN * DD;
    float* erow = eidx + (NN * KT + NN);
    float* lp = erow + (NN * KT + NN);
#pragma unroll
    for (int r = 0; r < 4; ++r) {
        eidx[i * 4 + r] = (float)mj[r];
        erow[i * 4 + r] = (float)i;
        lp[i * 4 + r] = mv[r];
    }
    eidx[NN * KT + i] = (float)i;
    erow[NN * KT + i] = (float)i;
}

extern "C" void kernel_launch(void* const* d_in, const int* in_sizes, int n_in,
                              void* d_out, int out_size, void* d_ws, size_t ws_size,
                              hipStream_t stream) {
    const float* x = (const float*)d_in[0];
    const int* ei = (const int*)d_in[1];
    const float* q = (const float*)d_in[2];
    const float* W = (const float*)d_in[3];
    const float* b = (const float*)d_in[4];
    const float* temp = (const float*)d_in[5];
    float* out = (float*)d_out;

    char* ws = (char*)d_ws;
    // lifetimes: hpre,acc die before k_prep; hhi/hlo/pvals/pidx overlay them.
    float* hpre = (float*)(ws + 0);                        // [0, 5.12e6)
    long long* acc = (long long*)(ws + 5120000);           // [5.12e6, 15.36e6)
    float* deg = (float*)(ws + 15360000);                  // 40,000
    float* dinv = (float*)(ws + 15400000);                 // 40,000
    float* sq = (float*)(ws + 15440000);                   // 40,192 (10048 rows)
    unsigned short* hhi = (unsigned short*)(ws + 0);       // 2,572,288 (over hpre)
    unsigned short* hlo = (unsigned short*)(ws + 2572288); // 2,572,288 (over hpre/acc head)
    float* pvals = (float*)(ws + 5144576);                 // 2,560,000 (inside acc)
    int* pidx = (int*)(ws + 7704576);                      // 2,560,000 (inside acc)

    // zero acc + deg each launch (ws poisoned once, never restored)
    hipMemsetAsync(ws + 5120000, 0, 10240000 + 40000, stream);

    k_gemm<<<NN, 128, 0, stream>>>(x, W, hpre);
    k_deg<<<(EE + 255) / 256, 256, 0, stream>>>(ei, deg);
    k_dinv<<<(NN + 255) / 256, 256, 0, stream>>>(deg, dinv);
    k_self<<<(NN * DD + 255) / 256, 256, 0, stream>>>(hpre, dinv, acc);
    k_agg<<<(EE * 32 + 255) / 256, 256, 0, stream>>>(ei, hpre, dinv, (unsigned long long*)acc);
    k_hfin<<<(NN * DD + 255) / 256, 256, 0, stream>>>(acc, b, out);
    k_prep<<<NPAD, 64, 0, stream>>>(out, hhi, hlo, sq);
    k_topk<<<ITILES * JSPLIT, 256, 0, stream>>>(hhi, hlo, sq, q, temp, pvals, pidx);
    k_merge<<<(NN + 255) / 256, 256, 0, stream>>>(pvals, pidx, out);
}

// Round 4
// 454.632 us; speedup vs baseline: 3.4857x; 2.9475x over previous
//
#include <hip/hip_runtime.h>

#define NN 10000
#define NPAD 10112
#define EE 160000
#define DD 128
#define KT 4

constexpr int JSPLIT = 16;
constexpr int ITILES = 157;                 // ceil(10000/64)
constexpr int JCHUNK = 628;                 // multiple of 4 -> 16B-aligned q float4 loads
constexpr double FPSCALE = 1099511627776.0; // 2^40
constexpr float NEG_INF = -3.402823466e38f;
constexpr float NLN2 = -0.69314718055994531f;

typedef __attribute__((ext_vector_type(8))) short short8;
typedef __attribute__((ext_vector_type(8))) unsigned short ushort8;
typedef __attribute__((ext_vector_type(4))) float f32x4;

// -------------------- bf16 split helpers --------------------
__device__ inline unsigned short bf_rn(float x) {
    unsigned u = __float_as_uint(x);
    unsigned r = (u + 0x7fffu + ((u >> 16) & 1u)) >> 16;
    return (unsigned short)r;
}
__device__ inline float bf_f(unsigned short h) {
    return __uint_as_float(((unsigned)h) << 16);
}

// -------------------- fast accurate ln (relative accuracy kept near x=1) ----------
// Direct atanh-series path on (0.6875, 1.375) avoids the catastrophic relative
// error hardware v_log_f32 has for ln(1+eps). REQUIRED for the inner gumbel log:
// q~1 candidates are the top-k winners and need u = -ln(q+1e-8) to ~1e-5 relative.
__device__ inline float fast_ln(float x) {
    int bits = __float_as_int(x);
    int e = ((bits >> 23) & 0xff) - 127;
    float m = __int_as_float((bits & 0x007fffff) | 0x3f800000); // [1,2)
    bool direct = (x > 0.6875f) && (x < 1.375f);
    float xm = direct ? x : m;
    float ef = direct ? 0.f : (float)e;
    float t = (xm - 1.f) * __builtin_amdgcn_rcpf(xm + 1.f);
    float t2 = t * t;
    float p = 0.09090909f;               // 1/11
    p = fmaf(p, t2, 0.11111111f);        // 1/9
    p = fmaf(p, t2, 0.14285714f);        // 1/7
    p = fmaf(p, t2, 0.2f);               // 1/5
    p = fmaf(p, t2, 0.33333333f);        // 1/3
    p = fmaf(p, t2, 1.f);
    p = 2.f * t * p;
    return fmaf(ef, 0.69314718055994531f, p);
}

// -------------------- h0 = x @ W --------------------
__global__ void k_gemm(const float* __restrict__ x, const float* __restrict__ W,
                       float* __restrict__ hpre) {
    int row = blockIdx.x;
    int c = threadIdx.x;   // 128
    __shared__ float xs[DD];
    xs[c] = x[row * DD + c];
    __syncthreads();
    float acc = 0.f;
#pragma unroll 8
    for (int k = 0; k < DD; ++k) acc += xs[k] * W[k * DD + c];
    hpre[row * DD + c] = acc;
}

// -------------------- CSR build: count -> scan(+dinv) -> fill --------------------
__global__ void k_count(const int* __restrict__ ei, int* __restrict__ cnt) {
    int e = blockIdx.x * blockDim.x + threadIdx.x;
    if (e < EE) atomicAdd(&cnt[ei[e]], 1);
}

__global__ void k_scan(int* __restrict__ cnt, int* __restrict__ rowptr,
                       float* __restrict__ dinv) {
    __shared__ int part[1024];
    int t = threadIdx.x;
    int base = t * 10;
    int loc[10];
    int s = 0;
#pragma unroll
    for (int k = 0; k < 10; ++k) {
        int idx = base + k;
        int v = (idx < NN) ? cnt[idx] : 0;
        loc[k] = s; s += v;
    }
    part[t] = s;
    __syncthreads();
    for (int off = 1; off < 1024; off <<= 1) {
        int v = (t >= off) ? part[t - off] : 0;
        __syncthreads();
        part[t] += v;
        __syncthreads();
    }
    int pre = (t > 0) ? part[t - 1] : 0;
#pragma unroll
    for (int k = 0; k < 10; ++k) {
        int idx = base + k;
        if (idx < NN) {
            rowptr[idx] = pre + loc[k];
            int d = cnt[idx];
            dinv[idx] = 1.0f / sqrtf((float)(d + 1));  // + self loop
            cnt[idx] = 0;  // reset for fill phase
        }
    }
    if (t == 1023) rowptr[NN] = part[1023];
}

__global__ void k_fill(const int* __restrict__ ei, const int* __restrict__ rowptr,
                       int* __restrict__ wcnt, int* __restrict__ csr) {
    int e = blockIdx.x * blockDim.x + threadIdx.x;
    if (e >= EE) return;
    int r = ei[e];
    int pos = atomicAdd(&wcnt[r], 1);
    csr[rowptr[r] + pos] = ei[EE + e];
}

// -------------------- deterministic gather: h = sym-norm agg + b -----------------
// i64 fixed-point accumulation is order-independent -> deterministic regardless of
// csr bucket order; numerics bit-identical to the round-2 atomic version.
__global__ void k_gather(const float* __restrict__ hpre, const int* __restrict__ rowptr,
                         const int* __restrict__ csr, const float* __restrict__ dinv,
                         const float* __restrict__ b, float* __restrict__ out) {
    int r = blockIdx.x;
    int t = threadIdx.x;  // 128
    float dr = dinv[r];
    float v0 = hpre[r * DD + t] * dr * dr;
    long long acc = llrint((double)v0 * FPSCALE);
    int s = rowptr[r], e = rowptr[r + 1];
    for (int k = s; k < e; ++k) {
        int c = csr[k];
        float w = dr * dinv[c];
        float p = hpre[c * DD + t] * w;
        acc += llrint((double)p * FPSCALE);
    }
    out[r * DD + t] = (float)((double)acc * (1.0 / FPSCALE)) + b[t];
}

// -------------------- bf16 hi/lo split + row norms (padded rows) --------------------
__global__ void k_prep(const float* __restrict__ h, unsigned short* __restrict__ hhi,
                       unsigned short* __restrict__ hlo, float* __restrict__ sqout) {
    int row = blockIdx.x;      // NPAD
    int c = threadIdx.x;       // 64
    float v0 = 0.f, v1 = 0.f;
    if (row < NN) { v0 = h[row * DD + c]; v1 = h[row * DD + 64 + c]; }
    unsigned short h0 = bf_rn(v0), h1 = bf_rn(v1);
    float r0 = v0 - bf_f(h0), r1 = v1 - bf_f(h1);
    unsigned short l0 = bf_rn(r0), l1 = bf_rn(r1);
    hhi[row * DD + c] = h0; hhi[row * DD + 64 + c] = h1;
    hlo[row * DD + c] = l0; hlo[row * DD + 64 + c] = l1;
    float s = v0 * v0 + v1 * v1;
#pragma unroll
    for (int off = 32; off; off >>= 1) s += __shfl_xor(s, off, 64);
    if (c == 0) sqout[row] = s;
}

#define BETTER(v1, j1, v2, j2) ((v1) > (v2) || ((v1) == (v2) && (j1) < (j2)))

// -------------------- MFMA pairwise-dist + gumbel + top-4 --------------------
// Operand-swapped: D = mfma(A=j-rows(LDS), B=i-rows(regs)) so D-col = i (lane&15),
// D-row = j (4 consecutive per lane) -> q read as one float4 per lane per jf.
__global__ __launch_bounds__(256, 4) void k_topk(
    const unsigned short* __restrict__ hhi, const unsigned short* __restrict__ hlo,
    const float* __restrict__ sq, const float* __restrict__ q,
    const float* __restrict__ tptr, float* __restrict__ pvals, int* __restrict__ pidx) {
    __shared__ __align__(16) unsigned short Bhi[64 * DD];  // 16 KB (j-tile hi)
    __shared__ __align__(16) unsigned short Blo[64 * DD];  // 16 KB (j-tile lo)
    __shared__ float sqs[64];

    const int blk = blockIdx.x;
    const int itile = blk >> 4;
    const int split = blk & 15;
    const int ibase = itile * 64;
    const int jstart = split * JCHUNK;
    const int jlimit = min(NN, jstart + JCHUNK);
    const float T = *tptr;

    const int tid = threadIdx.x;
    const int w = tid >> 6;
    const int lane = tid & 63;
    const int n = lane & 15;     // i-col within wave strip / B col
    const int kl = lane >> 4;    // k-slice group; D row group

    // ---- i-side register fragments (B operand): row ibase+16w+n ----
    short8 ihi[4], ilo[4];
    {
        int ra = ibase + 16 * w + n;        // <= 10047 < NPAD
        const unsigned short* pa = hhi + ra * DD + kl * 8;
        const unsigned short* pl = hlo + ra * DD + kl * 8;
#pragma unroll
        for (int ks = 0; ks < 4; ++ks) {
            ihi[ks] = *reinterpret_cast<const short8*>(pa + ks * 32);
            ilo[ks] = *reinterpret_cast<const short8*>(pl + ks * 32);
        }
    }

    const int i_glob = ibase + 16 * w + n;
    const int ic = min(i_glob, NN - 1);
    const float sqi = sq[ic];
    const float* qrow = q + (size_t)ic * NN;

    float tv[4];
    int tj[4];
#pragma unroll
    for (int s = 0; s < 4; ++s) { tv[s] = NEG_INF; tj[s] = 0x7fffffff; }

    for (int jt = 0; jt < 10; ++jt) {
        const int jbase = jstart + jt * 64;
        __syncthreads();  // previous-tile LDS reads done
        // ---- stage j-tile (hi+lo) with 16B-chunk XOR swizzle; stage sq slice ----
#pragma unroll
        for (int p = 0; p < 4; ++p) {
            int c = p * 256 + tid;
            int row = c >> 4, cl = c & 15;
            int cp = cl ^ (row & 7);
            int gsrc = (jbase + row) * DD + cl * 8;   // row <= 10059 < NPAD
            ushort8 vh = *reinterpret_cast<const ushort8*>(hhi + gsrc);
            ushort8 vl = *reinterpret_cast<const ushort8*>(hlo + gsrc);
            *reinterpret_cast<ushort8*>(&Bhi[row * DD + cp * 8]) = vh;
            *reinterpret_cast<ushort8*>(&Blo[row * DD + cp * 8]) = vl;
        }
        if (tid < 64) sqs[tid] = sq[jbase + tid];
        __syncthreads();

        // ---- q prefetch: one float4 per jf (j = jbase + 16jf + kl*4 + 0..3) ----
        float4 qv[4];
        const int j0base = jbase + kl * 4;
#pragma unroll
        for (int jf = 0; jf < 4; ++jf) {
            int j0 = j0base + 16 * jf;
            int jq = min(j0, NN - 4);       // clamp padded tail (masked later); 16B aligned
            qv[jf] = *reinterpret_cast<const float4*>(qrow + jq);
        }

#pragma unroll
        for (int jf = 0; jf < 4; ++jf) {
            const int arow = 16 * jf + n;
            const int xr = n & 7;
            short8 jh[4], jl[4];
#pragma unroll
            for (int ks = 0; ks < 4; ++ks) {
                int cp = (ks * 4 + kl) ^ xr;
                jh[ks] = *reinterpret_cast<const short8*>(&Bhi[arow * DD + cp * 8]);
                jl[ks] = *reinterpret_cast<const short8*>(&Blo[arow * DD + cp * 8]);
            }
            f32x4 acc = {0.f, 0.f, 0.f, 0.f};
#pragma unroll
            for (int ks = 0; ks < 4; ++ks)
                acc = __builtin_amdgcn_mfma_f32_16x16x32_bf16(jh[ks], ihi[ks], acc, 0, 0, 0);
#pragma unroll
            for (int ks = 0; ks < 4; ++ks)
                acc = __builtin_amdgcn_mfma_f32_16x16x32_bf16(jl[ks], ihi[ks], acc, 0, 0, 0);
#pragma unroll
            for (int ks = 0; ks < 4; ++ks)
                acc = __builtin_amdgcn_mfma_f32_16x16x32_bf16(jh[ks], ilo[ks], acc, 0, 0, 0);

            // ---- epilogue: 4 consecutive j for this lane's single i ----
            const float4 sq4 = *reinterpret_cast<const float4*>(&sqs[16 * jf + kl * 4]);
            const int j0 = j0base + 16 * jf;
            const float* sqp = reinterpret_cast<const float*>(&sq4);
            const float* qp = reinterpret_cast<const float*>(&qv[jf]);
#pragma unroll
            for (int r = 0; r < 4; ++r) {
                int j = j0 + r;
                float d2 = fmaxf(fmaf(-2.f, acc[r], sqi + sqp[r]), 0.f);
                float u = -fast_ln(qp[r] + 1e-8f);         // relative-accurate near q~1
                float g = __log2f(u) * NLN2;               // -ln(u); abs err ~1e-7 ok
                float v = (j < jlimit) ? fmaf(-T, d2, g) : NEG_INF;
                if (BETTER(v, j, tv[3], tj[3])) {
                    tv[3] = v; tj[3] = j;
#pragma unroll
                    for (int rr = 3; rr > 0; --rr) {
                        if (BETTER(tv[rr], tj[rr], tv[rr - 1], tj[rr - 1])) {
                            float t0 = tv[rr]; tv[rr] = tv[rr - 1]; tv[rr - 1] = t0;
                            int t1 = tj[rr]; tj[rr] = tj[rr - 1]; tj[rr - 1] = t1;
                        }
                    }
                }
            }
        }
    }

    // ---- in-block merge: 4 kl-lanes per i-row ----
    __syncthreads();
    float* mv = reinterpret_cast<float*>(Bhi);  // 64 rows x 16 entries
    int* mj = reinterpret_cast<int*>(Blo);
    {
        int rl = 16 * w + n;
#pragma unroll
        for (int s = 0; s < 4; ++s) {
            mv[rl * 16 + kl * 4 + s] = tv[s];
            mj[rl * 16 + kl * 4 + s] = tj[s];
        }
    }
    __syncthreads();
    if (tid < 64) {
        int i = ibase + tid;
        float bv[4] = {NEG_INF, NEG_INF, NEG_INF, NEG_INF};
        int bj[4] = {0x7fffffff, 0x7fffffff, 0x7fffffff, 0x7fffffff};
        for (int c = 0; c < 16; ++c) {
            float v = mv[tid * 16 + c];
            int j = mj[tid * 16 + c];
            if (BETTER(v, j, bv[3], bj[3])) {
                bv[3] = v; bj[3] = j;
#pragma unroll
                for (int rr = 3; rr > 0; --rr) {
                    if (BETTER(bv[rr], bj[rr], bv[rr - 1], bj[rr - 1])) {
                        float t0 = bv[rr]; bv[rr] = bv[rr - 1]; bv[rr - 1] = t0;
                        int t1 = bj[rr]; bj[rr] = bj[rr - 1]; bj[rr - 1] = t1;
                    }
                }
            }
        }
        if (i < NN) {
#pragma unroll
            for (int s = 0; s < 4; ++s) {
                pvals[(split * NN + i) * 4 + s] = bv[s];
                pidx[(split * NN + i) * 4 + s] = bj[s];
            }
        }
    }
}

// -------------------- final cross-split merge + output assembly --------------------
__global__ void k_merge(const float* __restrict__ pvals, const int* __restrict__ pidx,
                        float* __restrict__ out) {
    int i = blockIdx.x * blockDim.x + threadIdx.x;
    if (i >= NN) return;
    float mv[4] = {NEG_INF, NEG_INF, NEG_INF, NEG_INF};
    int mj[4] = {0x7fffffff, 0x7fffffff, 0x7fffffff, 0x7fffffff};
    for (int s = 0; s < JSPLIT; ++s) {
#pragma unroll
        for (int r = 0; r < 4; ++r) {
            float v = pvals[(s * NN + i) * 4 + r];
            int j = pidx[(s * NN + i) * 4 + r];
            if (BETTER(v, j, mv[3], mj[3])) {
                mv[3] = v; mj[3] = j;
#pragma unroll
                for (int rr = 3; rr > 0; --rr) {
                    if (BETTER(mv[rr], mj[rr], mv[rr - 1], mj[rr - 1])) {
                        float t0 = mv[rr]; mv[rr] = mv[rr - 1]; mv[rr - 1] = t0;
                        int t1 = mj[rr]; mj[rr] = mj[rr - 1]; mj[rr - 1] = t1;
                    }
                }
            }
        }
    }
    float* eidx = out + NN * DD;
    float* erow = eidx + (NN * KT + NN);
    float* lp = erow + (NN * KT + NN);
#pragma unroll
    for (int r = 0; r < 4; ++r) {
        eidx[i * 4 + r] = (float)mj[r];
        erow[i * 4 + r] = (float)i;
        lp[i * 4 + r] = mv[r];
    }
    eidx[NN * KT + i] = (float)i;
    erow[NN * KT + i] = (float)i;
}

extern "C" void kernel_launch(void* const* d_in, const int* in_sizes, int n_in,
                              void* d_out, int out_size, void* d_ws, size_t ws_size,
                              hipStream_t stream) {
    const float* x = (const float*)d_in[0];
    const int* ei = (const int*)d_in[1];
    const float* q = (const float*)d_in[2];
    const float* W = (const float*)d_in[3];
    const float* b = (const float*)d_in[4];
    const float* temp = (const float*)d_in[5];
    float* out = (float*)d_out;

    char* ws = (char*)d_ws;
    float* hpre = (float*)(ws + 0);                         // [0, 5,120,000) dies at k_gather
    unsigned short* hhi = (unsigned short*)(ws + 0);        // 2,588,672 (overlays hpre)
    unsigned short* hlo = (unsigned short*)(ws + 2588672);  // -> 5,177,344
    float* pvals = (float*)(ws + 5177344);                  // 2,560,000 -> 7,737,344
    int* pidx = (int*)(ws + 7737344);                       // 2,560,000 -> 10,297,344
    float* sq = (float*)(ws + 10297344);                    // 40,448 -> 10,337,792
    int* cnt = (int*)(ws + 10337792);                       // 40,000 -> 10,377,792 (also wcnt)
    int* rowptr = (int*)(ws + 10377792);                    // 40,016 -> 10,417,808
    float* dinv = (float*)(ws + 10417808);                  // 40,000 -> 10,457,808
    int* csr = (int*)(ws + 10457808);                       // 640,000 -> 11,097,808

    // zero edge-count histogram each launch (ws poisoned once, never restored)
    hipMemsetAsync(cnt, 0, 40000, stream);

    k_gemm<<<NN, 128, 0, stream>>>(x, W, hpre);
    k_count<<<(EE + 255) / 256, 256, 0, stream>>>(ei, cnt);
    k_scan<<<1, 1024, 0, stream>>>(cnt, rowptr, dinv);
    k_fill<<<(EE + 255) / 256, 256, 0, stream>>>(ei, rowptr, cnt, csr);
    k_gather<<<NN, 128, 0, stream>>>(hpre, rowptr, csr, dinv, b, out);
    k_prep<<<NPAD, 64, 0, stream>>>(out, hhi, hlo, sq);
    k_topk<<<ITILES * JSPLIT, 256, 0, stream>>>(hhi, hlo, sq, q, temp, pvals, pidx);
    k_merge<<<(NN + 255) / 256, 256, 0, stream>>>(pvals, pidx, out);
}